// Round 3
// baseline (217.509 us; speedup 1.0000x reference)
//
#include <hip/hip_runtime.h>
#include <hip/hip_bf16.h>
#include <stdint.h>

#define OUTN   8192
#define INN    8192
#define NGRP   64
#define BATCHN 64
#define KSPLIT 8
#define KCHUNK (INN / KSPLIT)   /* 1024 */
#define NITER  (KCHUNK / 128)   /* 8 groups of 128 per chunk */
#define OSZ    (BATCHN * OUTN)  /* 524288 floats = 2 MB */

typedef __attribute__((ext_vector_type(8))) short bf16x8;
typedef __attribute__((ext_vector_type(4))) float f32x4;
typedef __attribute__((ext_vector_type(4))) unsigned int u32x4;

__device__ __forceinline__ unsigned short f2bf(float f) {
  __hip_bfloat16 h = __float2bfloat16(f);
  return __builtin_bit_cast(unsigned short, h);
}
__device__ __forceinline__ float bf2f(unsigned short h) {
  unsigned int u = ((unsigned int)h) << 16;
  return __builtin_bit_cast(float, u);
}

// xsum[g][b] = sum over k in group g of bf16-rounded x[b][k]  (64x64 fp32)
__global__ void qlin_prep(const float* __restrict__ x, float* __restrict__ xsum) {
  const int b = blockIdx.x;
  const int t = threadIdx.x;
  const float* xrow = x + (size_t)b * INN + t * 32;
  float s = 0.0f;
#pragma unroll
  for (int i = 0; i < 8; ++i) {
    float4 v = *(const float4*)(xrow + i * 4);
    s += bf2f(f2bf(v.x)) + bf2f(f2bf(v.y)) + bf2f(f2bf(v.z)) + bf2f(f2bf(v.w));
  }
  __shared__ float part[256];
  part[t] = s;
  __syncthreads();
  if (t < NGRP) {
    float g = part[4 * t] + part[4 * t + 1] + part[4 * t + 2] + part[4 * t + 3];
    xsum[t * BATCHN + b] = g;
  }
}

// xswz[kb][b][j] = bf16(x[b][kb*8+j])  — A-fragment-major layout, 1 MB.
// A-frag for lane (q,r), tile (i,kq,mt): 16 B at ((kb)*64 + mt*16 + r)*8 shorts,
// kb = ks*128 + i*16 + kq*4 + q.
__global__ void qlin_swz(const float* __restrict__ x, unsigned short* __restrict__ xswz) {
  const int idx = blockIdx.x * 256 + threadIdx.x;  // 0..65535
  const int b  = idx & 63;
  const int kb = idx >> 6;
  const float* p = x + (size_t)b * INN + kb * 8;
  float4 v0 = *(const float4*)p;
  float4 v1 = *(const float4*)(p + 4);
  u32x4 o;
  o.x = (unsigned)f2bf(v0.x) | ((unsigned)f2bf(v0.y) << 16);
  o.y = (unsigned)f2bf(v0.z) | ((unsigned)f2bf(v0.w) << 16);
  o.z = (unsigned)f2bf(v1.x) | ((unsigned)f2bf(v1.y) << 16);
  o.w = (unsigned)f2bf(v1.z) | ((unsigned)f2bf(v1.w) << 16);
  *(u32x4*)&xswz[(size_t)idx * 8] = o;
}

__global__ __launch_bounds__(256, 4) void qlin_main(
    const int* __restrict__ packed, const float* __restrict__ scales,
    const unsigned short* __restrict__ xswz, const float* __restrict__ xsum,
    float* __restrict__ out, float* __restrict__ part) {
  const int bx    = blockIdx.x;
  const int ks    = bx & (KSPLIT - 1);
  const int ntile = bx >> 3;
  const int o0    = ntile * 64;
  const int g0    = ks * NITER;

  const int t    = threadIdx.x;
  const int lane = t & 63;
  const int w    = t >> 6;
  const int r    = lane & 15;
  const int q    = lane >> 4;
  const int orow = o0 + w * 16 + r;   // this lane's weight row / output col

  // xsum staged to LDS once (fold reads use lgkmcnt -> never drain global pipe)
  __shared__ float xs[NITER][BATCHN];  // 2 KB
#pragma unroll
  for (int i = 0; i < 2; ++i) {
    int v = t * 2 + i;
    xs[v >> 6][v & 63] = xsum[(g0 + (v >> 6)) * BATCHN + (v & 63)];
  }

  // per-lane scales for its row, groups g0..g0+7
  float4 sa = *(const float4*)&scales[(size_t)orow * NGRP + g0];
  float4 sb = *(const float4*)&scales[(size_t)orow * NGRP + g0 + 4];
  float sreg[8] = {sa.x, sa.y, sa.z, sa.w, sb.x, sb.y, sb.z, sb.w};

  // B: 4 consecutive int32 = 4 bytes = 8 nibbles = one MFMA k-slice, direct load
  const int* bptr = packed + (size_t)orow * (INN / 2) + ks * (KCHUNK / 2) + q * 4;
  // A: fragment-major bf16, L2-resident
  const unsigned short* aptr = xswz + ((size_t)(ks * 128 + q) * 64 + r) * 8;

  __syncthreads();  // only barrier: xs visible

  f32x4 facc[4];
#pragma unroll
  for (int mt = 0; mt < 4; ++mt) facc[mt] = (f32x4){0.f, 0.f, 0.f, 0.f};

  int4 b4[4], b4n[4];
#pragma unroll
  for (int kq = 0; kq < 4; ++kq) b4[kq] = *(const int4*)(bptr + kq * 16);

  for (int i = 0; i < NITER; ++i) {
    f32x4 gacc[4];
#pragma unroll
    for (int mt = 0; mt < 4; ++mt) gacc[mt] = (f32x4){0.f, 0.f, 0.f, 0.f};

#pragma unroll
    for (int kq = 0; kq < 4; ++kq) {
      bf16x8 af[4];
#pragma unroll
      for (int mt = 0; mt < 4; ++mt)
        af[mt] = *(const bf16x8*)(aptr + ((size_t)(i * 16 + kq * 4) * 64 + mt * 16) * 8);

      // dequant: byte v -> bf16 pair (128+lo | 128+hi) = 0x4300|nibble, exact
      int4 c = b4[kq];
      u32x4 bw0, bw1;
      bw0.x = 0x43004300u | ((unsigned)c.x & 0xFu) | (((unsigned)c.x & 0xF0u) << 12);
      bw0.y = 0x43004300u | ((unsigned)c.y & 0xFu) | (((unsigned)c.y & 0xF0u) << 12);
      bw0.z = 0x43004300u | ((unsigned)c.z & 0xFu) | (((unsigned)c.z & 0xF0u) << 12);
      bw0.w = 0x43004300u | ((unsigned)c.w & 0xFu) | (((unsigned)c.w & 0xF0u) << 12);
      bf16x8 bfv;
      bfv[0] = (short)(bw0.x & 0xFFFF); bfv[1] = (short)(bw0.x >> 16);
      bfv[2] = (short)(bw0.y & 0xFFFF); bfv[3] = (short)(bw0.y >> 16);
      bfv[4] = (short)(bw0.z & 0xFFFF); bfv[5] = (short)(bw0.z >> 16);
      bfv[6] = (short)(bw0.w & 0xFFFF); bfv[7] = (short)(bw0.w >> 16);
      (void)bw1;

#pragma unroll
      for (int mt = 0; mt < 4; ++mt)
        gacc[mt] = __builtin_amdgcn_mfma_f32_16x16x32_bf16(af[mt], bfv, gacc[mt], 0, 0, 0);
    }

    // prefetch next iter's B (newest in vmcnt FIFO -> stays in flight longest)
    if (i + 1 < NITER) {
#pragma unroll
      for (int kq = 0; kq < 4; ++kq)
        b4n[kq] = *(const int4*)(bptr + (i + 1) * 64 + kq * 16);
    }

    // fold group i: y += s[o,g] * (S_g - 136 * xsum_g[b])   (xs from LDS)
    float s0 = sreg[i];
#pragma unroll
    for (int mt = 0; mt < 4; ++mt) {
      f32x4 xv = *(const f32x4*)&xs[i][mt * 16 + q * 4];
#pragma unroll
      for (int rr = 0; rr < 4; ++rr)
        facc[mt][rr] += s0 * (gacc[mt][rr] - 136.0f * xv[rr]);
    }

#pragma unroll
    for (int kq = 0; kq < 4; ++kq) b4[kq] = b4n[kq];
  }

  if (part) {
    float* pb = part + (size_t)ks * OSZ;
#pragma unroll
    for (int mt = 0; mt < 4; ++mt)
#pragma unroll
      for (int rr = 0; rr < 4; ++rr) {
        int m = mt * 16 + q * 4 + rr;
        pb[(size_t)m * OUTN + orow] = facc[mt][rr];
      }
  } else {
#pragma unroll
    for (int mt = 0; mt < 4; ++mt)
#pragma unroll
      for (int rr = 0; rr < 4; ++rr) {
        int m = mt * 16 + q * 4 + rr;
        atomicAdd(&out[(size_t)m * OUTN + orow], facc[mt][rr]);
      }
  }
}

__global__ void qlin_reduce(const float* __restrict__ part, float* __restrict__ out) {
  const size_t i = ((size_t)blockIdx.x * 256 + threadIdx.x) * 4;
  float4 s = *(const float4*)(part + i);
#pragma unroll
  for (int ks = 1; ks < KSPLIT; ++ks) {
    float4 v = *(const float4*)(part + (size_t)ks * OSZ + i);
    s.x += v.x; s.y += v.y; s.z += v.z; s.w += v.w;
  }
  *(float4*)(out + i) = s;
}

extern "C" void kernel_launch(void* const* d_in, const int* in_sizes, int n_in,
                              void* d_out, int out_size, void* d_ws, size_t ws_size,
                              hipStream_t stream) {
  const float* x      = (const float*)d_in[0];
  const int*   packed = (const int*)d_in[1];
  const float* scales = (const float*)d_in[2];
  float* out = (float*)d_out;

  char* ws = (char*)d_ws;
  float*          xsum = (float*)ws;                          // 16 KB
  unsigned short* xswz = (unsigned short*)(ws + 16384);       // 1 MB
  const size_t part_need = 16384 + 1048576 + (size_t)KSPLIT * OSZ * sizeof(float);
  float* part = (ws_size >= part_need) ? (float*)(ws + 16384 + 1048576) : nullptr;

  qlin_prep<<<BATCHN, 256, 0, stream>>>(x, xsum);
  qlin_swz<<<(INN / 8) * BATCHN / 256, 256, 0, stream>>>(x, xswz);
  if (!part)
    hipMemsetAsync(d_out, 0, (size_t)out_size * sizeof(float), stream);
  qlin_main<<<(OUTN / 64) * KSPLIT, 256, 0, stream>>>(packed, scales, xswz, xsum, out, part);
  if (part)
    qlin_reduce<<<OSZ / 4 / 256, 256, 0, stream>>>(part, out);
}